// Round 15
// baseline (229.334 us; speedup 1.0000x reference)
//
#include <hip/hip_runtime.h>
#include <math.h>

#define SEQ   2048
#define DH    64
#define NBH   24
// scale * log2(e): softmax in exp2 domain
#define QSCALE 0.18033688011112042f

typedef __attribute__((ext_vector_type(8))) short short8;
typedef __attribute__((ext_vector_type(4))) short short4v;
typedef __attribute__((ext_vector_type(4))) float f32x4;

#define MFMA32(a, b, c) __builtin_amdgcn_mfma_f32_16x16x32_bf16((a), (b), (c), 0, 0, 0)
// gfx950 v_mfma_f32_16x16x16_bf16 (short4 operands) = the _1k builtin name.
#define MFMA16(a, b, c) __builtin_amdgcn_mfma_f32_16x16x16bf16_1k((a), (b), (c), 0, 0, 0)

// hardware RNE f32x2 -> packed bf16x2
__device__ __forceinline__ int cvtpk(float lo, float hi) {
    int r;
    asm("v_cvt_pk_bf16_f32 %0, %1, %2" : "=v"(r) : "v"(lo), "v"(hi));
    return r;
}

// ---- fused pre-pass, 32-row tiles, FRAGMENT-MAJOR outputs (R8 layout —
// dense 1KB wave segments took attn 97 -> ~43us; BW-bound at ~10us itself).
//   kb: per 16-seq block, 2KB chunk = two 1KB halves (d<32 | d>=32);
//       K[s][h*32 + quad*8 + r] at shorts[h*512 + (quad*16+(s&15))*8 + r].
//   vt: per (32-k-block, dt) 1KB chunk; lane(quad,l16) holds
//       V[k32+quad*4+i][dt*16+l16] (i<4) ++ V[k32+16+quad*4+i][...].
__global__ __launch_bounds__(256)
void cvt_all(const float* __restrict__ q, const float* __restrict__ k,
             const float* __restrict__ v,
             short* __restrict__ qb, short* __restrict__ kb,
             short* __restrict__ vt)
{
    __shared__ float tile[32][68];
    const int t  = threadIdx.x;
    const int bh = blockIdx.x;
    const int s0 = blockIdx.y * 32;
    const size_t base = ((size_t)bh * SEQ + s0) * DH;   // 32*64 f32 = 512 float4
    const size_t kbh  = (size_t)bh * SEQ * DH;

    #pragma unroll
    for (int i = 0; i < 2; ++i) {
        const int idx = i * 256 + t;
        float4 a = ((const float4*)(q + base))[idx];
        ((int2*)(qb + base))[idx] = make_int2(
            cvtpk(a.x * QSCALE, a.y * QSCALE),
            cvtpk(a.z * QSCALE, a.w * QSCALE));

        // K -> fragment-major
        float4 b = ((const float4*)(k + base))[idx];
        {
            const int sl   = idx >> 4;           // local row 0..31
            const int fgrp = idx & 15;           // float4-group = d0/4
            const int sblk = (s0 >> 4) + (sl >> 4);
            const int half = fgrp >> 3;
            const int quad = (fgrp >> 1) & 3;
            const int r04  = (fgrp & 1) * 4;
            short* p = kb + kbh + (size_t)sblk * 1024 + half * 512
                     + (quad * 16 + (sl & 15)) * 8 + r04;
            *(int2*)p = make_int2(cvtpk(b.x, b.y), cvtpk(b.z, b.w));
        }

        float4 c = ((const float4*)(v + base))[idx];
        const int sl = idx >> 4, cg = (idx & 15) * 4;
        *(float4*)(&tile[sl][cg]) = c;
    }
    __syncthreads();
    {
        const int dl = t >> 2;     // d index 0..63
        const int qq = t & 3;      // quarter within the 32-seq block
        float f[8];
        #pragma unroll
        for (int r = 0; r < 4; ++r) {
            f[r]     = tile[qq * 4 + r][dl];        // m=0 half
            f[4 + r] = tile[16 + qq * 4 + r][dl];   // m=1 half
        }
        short8 pc;
        ((int*)&pc)[0] = cvtpk(f[0], f[1]);
        ((int*)&pc)[1] = cvtpk(f[2], f[3]);
        ((int*)&pc)[2] = cvtpk(f[4], f[5]);
        ((int*)&pc)[3] = cvtpk(f[6], f[7]);
        // fragment-major: chunk (k32 = s0/32, dt = dl>>4), lane = qq*16+(dl&15)
        short* p = vt + kbh + (size_t)((s0 >> 5) * 4 + (dl >> 4)) * 512
                 + (qq * 16 + (dl & 15)) * 8;
        *(short8*)p = pc;
    }
}

// ---- main: 4-way split-K flash, 64 q-rows/wave (R10/R14 structure).
// DO NOT REMOVE the s_setprio toggles: R12/R13 measured that deleting them
// (a semantically-neutral diff) produces deterministic NaN — they act as
// scheduling fences around the cvtpk inline-asm / MFMA / prefetch chain.
// R15 single variable: the merge-epilogue LDS (70KB, used ~1% of lifetime)
// was capping residency at 2 blocks/CU. Split the merge into TWO passes
// (qs 0-1 then qs 2-3) -> LDS ~35KB -> 3 blocks/CU via (256,3); demand
// ~148 unified regs (84 arch + 64 acc) < 170 cap, so no spill expected.
// Rationale: R7's occupancy-null predates fragment-major (R8); in the
// current latency-bound regime TLP is the direct latency-cover multiplier
// (R9->R10: 1->2 waves/SIMD was part of 60->40us).
// Pre-committed: WRITE>14MB = spill -> R14 final; dur>=115 = null -> floor.
__global__ __launch_bounds__(256, 3)
void attn_fwd(const short* __restrict__ qb, const short* __restrict__ kb,
              const short* __restrict__ vt, float* __restrict__ og)
{
    __shared__ float lds_o[4][2][64][17];   // [wave][qh][lane][16] padded
    __shared__ float lds_l[4][2][16];

    const int lane = threadIdx.x & 63;
    const int wave = threadIdx.x >> 6;     // k-quarter 0..3
    const int quad = lane >> 4;
    const int l16  = lane & 15;
    const int lane8 = lane * 8;            // short offset of this lane's 16B

    // bijective XCD swizzle (768 = 8 XCD x 96): 3 bh per XCD -> K/V L2-resident
    const int swz = (blockIdx.x & 7) * 96 + (blockIdx.x >> 3);
    const int bh  = swz >> 5;              // 32 blocks per bh
    const int q0  = (swz & 31) * 64;       // 64 q-rows per block

    const short* kbase = kb + (size_t)bh * SEQ * DH;
    const short* vbase = vt + (size_t)bh * DH * SEQ;

    short8 bq[4][2];
    #pragma unroll
    for (int qs = 0; qs < 4; ++qs) {
        const short* qrow = qb + ((size_t)(bh * SEQ + q0 + qs * 16 + l16)) * DH + quad * 8;
        bq[qs][0] = *(const short8*)(qrow);
        bq[qs][1] = *(const short8*)(qrow + 32);
    }

    f32x4 o[4][4];
    float l_i[4];
    #pragma unroll
    for (int qs = 0; qs < 4; ++qs) {
        l_i[qs] = 0.f;
        #pragma unroll
        for (int dt = 0; dt < 4; ++dt) o[qs][dt] = (f32x4){0.f, 0.f, 0.f, 0.f};
    }

    int k0 = wave * (SEQ / 4);
    short8 ka[8];
    #pragma unroll
    for (int mt = 0; mt < 4; ++mt) {
        const short* kc = kbase + (size_t)((k0 >> 4) + mt) * 1024 + lane8;
        ka[2 * mt]     = *(const short8*)(kc);
        ka[2 * mt + 1] = *(const short8*)(kc + 512);
    }

    #pragma unroll 1
    for (int iter = 0; iter < 8; ++iter, k0 += 64) {
        // ---- V(i) loads first: dense 1KB segments
        short8 av[2][4];
        #pragma unroll
        for (int pair = 0; pair < 2; ++pair)
            #pragma unroll
            for (int dt = 0; dt < 4; ++dt)
                av[pair][dt] = *(const short8*)(vbase
                    + (size_t)((((k0 >> 5) + pair) * 4) + dt) * 512 + lane8);

        // ---- per q-subtile: QK^T -> fixed-frame exp2+pack -> PV (pb transient)
        #pragma unroll
        for (int qs = 0; qs < 4; ++qs) {
            f32x4 c[4];
            __builtin_amdgcn_s_setprio(1);
            #pragma unroll
            for (int mt = 0; mt < 4; ++mt) {
                f32x4 z = (f32x4){0.f, 0.f, 0.f, 0.f};
                z = MFMA32(ka[2 * mt],     bq[qs][0], z);
                z = MFMA32(ka[2 * mt + 1], bq[qs][1], z);
                c[mt] = z;
            }
            __builtin_amdgcn_s_setprio(0);

            // K(i+1) prefetch right after ka's last use (qs==3 QK^T)
            if (qs == 3 && iter < 7) {
                const int k0n = k0 + 64;
                #pragma unroll
                for (int mt = 0; mt < 4; ++mt) {
                    const short* kc = kbase + (size_t)((k0n >> 4) + mt) * 1024 + lane8;
                    ka[2 * mt]     = *(const short8*)(kc);
                    ka[2 * mt + 1] = *(const short8*)(kc + 512);
                }
            }

            // p = exp2(S) raw — fixed frame; cancels in (Sum p*v)/(Sum p).
            short4v pb[4];
            float rsm[4];
            #pragma unroll
            for (int mt = 0; mt < 4; ++mt) {
                float p[4];
                #pragma unroll
                for (int r = 0; r < 4; ++r)
                    p[r] = __builtin_amdgcn_exp2f(c[mt][r]);
                rsm[mt] = (p[0] + p[1]) + (p[2] + p[3]);
                int2 w = make_int2(cvtpk(p[0], p[1]), cvtpk(p[2], p[3]));
                pb[mt] = __builtin_bit_cast(short4v, w);
            }
            l_i[qs] += (rsm[0] + rsm[1]) + (rsm[2] + rsm[3]);

            // PV for this qs (av resident since iter top)
            __builtin_amdgcn_s_setprio(1);
            #pragma unroll
            for (int pair = 0; pair < 2; ++pair) {
                #pragma unroll
                for (int dt = 0; dt < 4; ++dt) {
                    const short4v alo = __builtin_shufflevector(av[pair][dt], av[pair][dt], 0, 1, 2, 3);
                    const short4v ahi = __builtin_shufflevector(av[pair][dt], av[pair][dt], 4, 5, 6, 7);
                    o[qs][dt] = MFMA16(alo, pb[2 * pair],     o[qs][dt]);
                    o[qs][dt] = MFMA16(ahi, pb[2 * pair + 1], o[qs][dt]);
                }
            }
            __builtin_amdgcn_s_setprio(0);
        }
    }

    // ---- finalize per-row l (cross-quad) once
    #pragma unroll
    for (int qs = 0; qs < 4; ++qs) {
        float l = l_i[qs];
        l += __shfl_xor(l, 16, 64);
        l += __shfl_xor(l, 32, 64);
        l_i[qs] = l;
    }

    // ---- 4-way cross-wave merge, TWO passes of 2 q-subtiles each (halves
    // the LDS footprint vs R14's single pass; epilogue-only cost).
    #pragma unroll 1
    for (int half = 0; half < 2; ++half) {
        __syncthreads();   // pass 0: after main loop; pass 1: protect reuse
        #pragma unroll
        for (int qh = 0; qh < 2; ++qh) {
            const int qs = half * 2 + qh;
            #pragma unroll
            for (int dt = 0; dt < 4; ++dt)
                #pragma unroll
                for (int r = 0; r < 4; ++r)
                    lds_o[wave][qh][lane][dt * 4 + r] = o[qs][dt][r];
            if (quad == 0) lds_l[wave][qh][l16] = l_i[qs];
        }
        __syncthreads();
        #pragma unroll
        for (int j = 0; j < 2; ++j) {
            const int s  = wave * 2 + j;   // 8 slices: (qh 0-1) x (dt 0-3)
            const int qh = s >> 2, dt = s & 3;
            const int qs = half * 2 + qh;
            const float L = (lds_l[0][qh][l16] + lds_l[1][qh][l16])
                          + (lds_l[2][qh][l16] + lds_l[3][qh][l16]);
            const float linv = 1.0f / L;
            f32x4 st;
            #pragma unroll
            for (int r = 0; r < 4; ++r)
                st[r] = ((lds_o[0][qh][lane][dt * 4 + r] + lds_o[1][qh][lane][dt * 4 + r])
                       + (lds_o[2][qh][lane][dt * 4 + r] + lds_o[3][qh][lane][dt * 4 + r]))
                      * linv;
            *(f32x4*)(og + ((size_t)(bh * SEQ + q0 + qs * 16 + l16)) * DH
                      + dt * 16 + quad * 4) = st;
        }
    }
}

extern "C" void kernel_launch(void* const* d_in, const int* in_sizes, int n_in,
                              void* d_out, int out_size, void* d_ws, size_t ws_size,
                              hipStream_t stream)
{
    const float* q = (const float*)d_in[0];
    const float* k = (const float*)d_in[1];
    const float* v = (const float*)d_in[2];
    float* o = (float*)d_out;

    const size_t nelem = (size_t)NBH * SEQ * DH;
    short* qb  = (short*)d_ws;
    short* kbp = qb + nelem;
    short* vtp = kbp + nelem;   // 18.9 MB total

    cvt_all<<<dim3(NBH, SEQ / 32), 256, 0, stream>>>(q, k, v, qb, kbp, vtp);
    attn_fwd<<<dim3(NBH * (SEQ / 64)), 256, 0, stream>>>(qb, kbp, vtp, o);
    // grid = 24 bh x 32 q-tiles of 64 rows = 768 blocks; 3 blocks/CU exactly
}

// Round 16
// 211.124 us; speedup vs baseline: 1.0863x; 1.0863x over previous
//
#include <hip/hip_runtime.h>
#include <math.h>

#define SEQ   2048
#define DH    64
#define NBH   24
// scale * log2(e): softmax in exp2 domain
#define QSCALE 0.18033688011112042f

typedef __attribute__((ext_vector_type(8))) short short8;
typedef __attribute__((ext_vector_type(4))) short short4v;
typedef __attribute__((ext_vector_type(4))) float f32x4;

#define MFMA32(a, b, c) __builtin_amdgcn_mfma_f32_16x16x32_bf16((a), (b), (c), 0, 0, 0)
// gfx950 v_mfma_f32_16x16x16_bf16 (short4 operands) = the _1k builtin name.
#define MFMA16(a, b, c) __builtin_amdgcn_mfma_f32_16x16x16bf16_1k((a), (b), (c), 0, 0, 0)

// hardware RNE f32x2 -> packed bf16x2
__device__ __forceinline__ int cvtpk(float lo, float hi) {
    int r;
    asm("v_cvt_pk_bf16_f32 %0, %1, %2" : "=v"(r) : "v"(lo), "v"(hi));
    return r;
}

// ---- fused pre-pass, 32-row tiles, FRAGMENT-MAJOR outputs (R8 layout —
// dense 1KB wave segments took attn 97 -> ~43us; BW-bound at ~10us itself).
//   kb: per 16-seq block, 2KB chunk = two 1KB halves (d<32 | d>=32);
//       K[s][h*32 + quad*8 + r] at shorts[h*512 + (quad*16+(s&15))*8 + r].
//   vt: per (32-k-block, dt) 1KB chunk; lane(quad,l16) holds
//       V[k32+quad*4+i][dt*16+l16] (i<4) ++ V[k32+16+quad*4+i][...].
__global__ __launch_bounds__(256)
void cvt_all(const float* __restrict__ q, const float* __restrict__ k,
             const float* __restrict__ v,
             short* __restrict__ qb, short* __restrict__ kb,
             short* __restrict__ vt)
{
    __shared__ float tile[32][68];
    const int t  = threadIdx.x;
    const int bh = blockIdx.x;
    const int s0 = blockIdx.y * 32;
    const size_t base = ((size_t)bh * SEQ + s0) * DH;   // 32*64 f32 = 512 float4
    const size_t kbh  = (size_t)bh * SEQ * DH;

    #pragma unroll
    for (int i = 0; i < 2; ++i) {
        const int idx = i * 256 + t;
        float4 a = ((const float4*)(q + base))[idx];
        ((int2*)(qb + base))[idx] = make_int2(
            cvtpk(a.x * QSCALE, a.y * QSCALE),
            cvtpk(a.z * QSCALE, a.w * QSCALE));

        // K -> fragment-major
        float4 b = ((const float4*)(k + base))[idx];
        {
            const int sl   = idx >> 4;           // local row 0..31
            const int fgrp = idx & 15;           // float4-group = d0/4
            const int sblk = (s0 >> 4) + (sl >> 4);
            const int half = fgrp >> 3;
            const int quad = (fgrp >> 1) & 3;
            const int r04  = (fgrp & 1) * 4;
            short* p = kb + kbh + (size_t)sblk * 1024 + half * 512
                     + (quad * 16 + (sl & 15)) * 8 + r04;
            *(int2*)p = make_int2(cvtpk(b.x, b.y), cvtpk(b.z, b.w));
        }

        float4 c = ((const float4*)(v + base))[idx];
        const int sl = idx >> 4, cg = (idx & 15) * 4;
        *(float4*)(&tile[sl][cg]) = c;
    }
    __syncthreads();
    {
        const int dl = t >> 2;     // d index 0..63
        const int qq = t & 3;      // quarter within the 32-seq block
        float f[8];
        #pragma unroll
        for (int r = 0; r < 4; ++r) {
            f[r]     = tile[qq * 4 + r][dl];        // m=0 half
            f[4 + r] = tile[16 + qq * 4 + r][dl];   // m=1 half
        }
        short8 pc;
        ((int*)&pc)[0] = cvtpk(f[0], f[1]);
        ((int*)&pc)[1] = cvtpk(f[2], f[3]);
        ((int*)&pc)[2] = cvtpk(f[4], f[5]);
        ((int*)&pc)[3] = cvtpk(f[6], f[7]);
        // fragment-major: chunk (k32 = s0/32, dt = dl>>4), lane = qq*16+(dl&15)
        short* p = vt + kbh + (size_t)((s0 >> 5) * 4 + (dl >> 4)) * 512
                 + (qq * 16 + (dl & 15)) * 8;
        *(short8*)p = pc;
    }
}

// ---- main: 4-way split-K flash, 64 q-rows/wave (R10/R14 structure).
// DO NOT REMOVE the s_setprio toggles: R12/R13 measured that deleting them
// (a semantically-neutral diff) produces deterministic NaN — they act as
// scheduling fences around the cvtpk inline-asm / MFMA / prefetch chain.
// R16 = R15's 3-blocks/CU experiment with the rule-#20 bug FIXED: R15's
// `#pragma unroll 1` on the epilogue half-loop made qs=half*2+qh runtime ->
// the WHOLE o[4][4] accumulator demoted to scratch (FETCH 276MB / WRITE
// 418MB, attn 152us). Fix: full unroll -> every o[qs] index compile-time.
// Two-pass merge keeps LDS at ~35KB -> 3 blocks/CU via (256,3); demand
// ~148 unified regs (84 arch + 64 acc) < 170 cap.
// Pre-committed (FINAL): WRITE>14MB or dur>=115 -> revert to R14, declare.
__global__ __launch_bounds__(256, 3)
void attn_fwd(const short* __restrict__ qb, const short* __restrict__ kb,
              const short* __restrict__ vt, float* __restrict__ og)
{
    __shared__ float lds_o[4][2][64][17];   // [wave][qh][lane][16] padded
    __shared__ float lds_l[4][2][16];

    const int lane = threadIdx.x & 63;
    const int wave = threadIdx.x >> 6;     // k-quarter 0..3
    const int quad = lane >> 4;
    const int l16  = lane & 15;
    const int lane8 = lane * 8;            // short offset of this lane's 16B

    // bijective XCD swizzle (768 = 8 XCD x 96): 3 bh per XCD -> K/V L2-resident
    const int swz = (blockIdx.x & 7) * 96 + (blockIdx.x >> 3);
    const int bh  = swz >> 5;              // 32 blocks per bh
    const int q0  = (swz & 31) * 64;       // 64 q-rows per block

    const short* kbase = kb + (size_t)bh * SEQ * DH;
    const short* vbase = vt + (size_t)bh * DH * SEQ;

    short8 bq[4][2];
    #pragma unroll
    for (int qs = 0; qs < 4; ++qs) {
        const short* qrow = qb + ((size_t)(bh * SEQ + q0 + qs * 16 + l16)) * DH + quad * 8;
        bq[qs][0] = *(const short8*)(qrow);
        bq[qs][1] = *(const short8*)(qrow + 32);
    }

    f32x4 o[4][4];
    float l_i[4];
    #pragma unroll
    for (int qs = 0; qs < 4; ++qs) {
        l_i[qs] = 0.f;
        #pragma unroll
        for (int dt = 0; dt < 4; ++dt) o[qs][dt] = (f32x4){0.f, 0.f, 0.f, 0.f};
    }

    int k0 = wave * (SEQ / 4);
    short8 ka[8];
    #pragma unroll
    for (int mt = 0; mt < 4; ++mt) {
        const short* kc = kbase + (size_t)((k0 >> 4) + mt) * 1024 + lane8;
        ka[2 * mt]     = *(const short8*)(kc);
        ka[2 * mt + 1] = *(const short8*)(kc + 512);
    }

    #pragma unroll 1
    for (int iter = 0; iter < 8; ++iter, k0 += 64) {
        // ---- V(i) loads first: dense 1KB segments
        short8 av[2][4];
        #pragma unroll
        for (int pair = 0; pair < 2; ++pair)
            #pragma unroll
            for (int dt = 0; dt < 4; ++dt)
                av[pair][dt] = *(const short8*)(vbase
                    + (size_t)((((k0 >> 5) + pair) * 4) + dt) * 512 + lane8);

        // ---- per q-subtile: QK^T -> fixed-frame exp2+pack -> PV (pb transient)
        #pragma unroll
        for (int qs = 0; qs < 4; ++qs) {
            f32x4 c[4];
            __builtin_amdgcn_s_setprio(1);
            #pragma unroll
            for (int mt = 0; mt < 4; ++mt) {
                f32x4 z = (f32x4){0.f, 0.f, 0.f, 0.f};
                z = MFMA32(ka[2 * mt],     bq[qs][0], z);
                z = MFMA32(ka[2 * mt + 1], bq[qs][1], z);
                c[mt] = z;
            }
            __builtin_amdgcn_s_setprio(0);

            // K(i+1) prefetch right after ka's last use (qs==3 QK^T)
            if (qs == 3 && iter < 7) {
                const int k0n = k0 + 64;
                #pragma unroll
                for (int mt = 0; mt < 4; ++mt) {
                    const short* kc = kbase + (size_t)((k0n >> 4) + mt) * 1024 + lane8;
                    ka[2 * mt]     = *(const short8*)(kc);
                    ka[2 * mt + 1] = *(const short8*)(kc + 512);
                }
            }

            // p = exp2(S) raw — fixed frame; cancels in (Sum p*v)/(Sum p).
            short4v pb[4];
            float rsm[4];
            #pragma unroll
            for (int mt = 0; mt < 4; ++mt) {
                float p[4];
                #pragma unroll
                for (int r = 0; r < 4; ++r)
                    p[r] = __builtin_amdgcn_exp2f(c[mt][r]);
                rsm[mt] = (p[0] + p[1]) + (p[2] + p[3]);
                int2 w = make_int2(cvtpk(p[0], p[1]), cvtpk(p[2], p[3]));
                pb[mt] = __builtin_bit_cast(short4v, w);
            }
            l_i[qs] += (rsm[0] + rsm[1]) + (rsm[2] + rsm[3]);

            // PV for this qs (av resident since iter top)
            __builtin_amdgcn_s_setprio(1);
            #pragma unroll
            for (int pair = 0; pair < 2; ++pair) {
                #pragma unroll
                for (int dt = 0; dt < 4; ++dt) {
                    const short4v alo = __builtin_shufflevector(av[pair][dt], av[pair][dt], 0, 1, 2, 3);
                    const short4v ahi = __builtin_shufflevector(av[pair][dt], av[pair][dt], 4, 5, 6, 7);
                    o[qs][dt] = MFMA16(alo, pb[2 * pair],     o[qs][dt]);
                    o[qs][dt] = MFMA16(ahi, pb[2 * pair + 1], o[qs][dt]);
                }
            }
            __builtin_amdgcn_s_setprio(0);
        }
    }

    // ---- finalize per-row l (cross-quad) once
    #pragma unroll
    for (int qs = 0; qs < 4; ++qs) {
        float l = l_i[qs];
        l += __shfl_xor(l, 16, 64);
        l += __shfl_xor(l, 32, 64);
        l_i[qs] = l;
    }

    // ---- 4-way cross-wave merge, TWO passes of 2 q-subtiles each. FULLY
    // UNROLLED (rule #20): half/qh/qs are all compile-time constants so
    // every o[qs] access stays in registers.
    #pragma unroll
    for (int half = 0; half < 2; ++half) {
        __syncthreads();   // pass 0: after main loop; pass 1: protect reuse
        #pragma unroll
        for (int qh = 0; qh < 2; ++qh) {
            const int qs = half * 2 + qh;
            #pragma unroll
            for (int dt = 0; dt < 4; ++dt)
                #pragma unroll
                for (int r = 0; r < 4; ++r)
                    lds_o[wave][qh][lane][dt * 4 + r] = o[qs][dt][r];
            if (quad == 0) lds_l[wave][qh][l16] = l_i[qs];
        }
        __syncthreads();
        #pragma unroll
        for (int j = 0; j < 2; ++j) {
            const int s  = wave * 2 + j;   // 8 slices: (qh 0-1) x (dt 0-3)
            const int qh = s >> 2, dt = s & 3;
            const int qs = half * 2 + qh;
            const float L = (lds_l[0][qh][l16] + lds_l[1][qh][l16])
                          + (lds_l[2][qh][l16] + lds_l[3][qh][l16]);
            const float linv = 1.0f / L;
            f32x4 st;
            #pragma unroll
            for (int r = 0; r < 4; ++r)
                st[r] = ((lds_o[0][qh][lane][dt * 4 + r] + lds_o[1][qh][lane][dt * 4 + r])
                       + (lds_o[2][qh][lane][dt * 4 + r] + lds_o[3][qh][lane][dt * 4 + r]))
                      * linv;
            *(f32x4*)(og + ((size_t)(bh * SEQ + q0 + qs * 16 + l16)) * DH
                      + dt * 16 + quad * 4) = st;
        }
    }
}

extern "C" void kernel_launch(void* const* d_in, const int* in_sizes, int n_in,
                              void* d_out, int out_size, void* d_ws, size_t ws_size,
                              hipStream_t stream)
{
    const float* q = (const float*)d_in[0];
    const float* k = (const float*)d_in[1];
    const float* v = (const float*)d_in[2];
    float* o = (float*)d_out;

    const size_t nelem = (size_t)NBH * SEQ * DH;
    short* qb  = (short*)d_ws;
    short* kbp = qb + nelem;
    short* vtp = kbp + nelem;   // 18.9 MB total

    cvt_all<<<dim3(NBH, SEQ / 32), 256, 0, stream>>>(q, k, v, qb, kbp, vtp);
    attn_fwd<<<dim3(NBH * (SEQ / 64)), 256, 0, stream>>>(qb, kbp, vtp, o);
    // grid = 24 bh x 32 q-tiles of 64 rows = 768 blocks; 3 blocks/CU exactly
}

// Round 17
// 115.307 us; speedup vs baseline: 1.9889x; 1.8310x over previous
//
#include <hip/hip_runtime.h>
#include <math.h>

#define SEQ   2048
#define DH    64
#define NBH   24
// scale * log2(e): softmax in exp2 domain
#define QSCALE 0.18033688011112042f

typedef __attribute__((ext_vector_type(8))) short short8;
typedef __attribute__((ext_vector_type(4))) short short4v;
typedef __attribute__((ext_vector_type(4))) float f32x4;

#define MFMA32(a, b, c) __builtin_amdgcn_mfma_f32_16x16x32_bf16((a), (b), (c), 0, 0, 0)
// gfx950 v_mfma_f32_16x16x16_bf16 (short4 operands) = the _1k builtin name.
#define MFMA16(a, b, c) __builtin_amdgcn_mfma_f32_16x16x16bf16_1k((a), (b), (c), 0, 0, 0)

// hardware RNE f32x2 -> packed bf16x2
__device__ __forceinline__ int cvtpk(float lo, float hi) {
    int r;
    asm("v_cvt_pk_bf16_f32 %0, %1, %2" : "=v"(r) : "v"(lo), "v"(hi));
    return r;
}

// ---- fused pre-pass, 32-row tiles, FRAGMENT-MAJOR outputs (R8 layout —
// dense 1KB wave segments took attn 97 -> ~43us; BW-bound at ~10us itself).
//   kb: per 16-seq block, 2KB chunk = two 1KB halves (d<32 | d>=32);
//       K[s][h*32 + quad*8 + r] at shorts[h*512 + (quad*16+(s&15))*8 + r].
//   vt: per (32-k-block, dt) 1KB chunk; lane(quad,l16) holds
//       V[k32+quad*4+i][dt*16+l16] (i<4) ++ V[k32+16+quad*4+i][...].
__global__ __launch_bounds__(256)
void cvt_all(const float* __restrict__ q, const float* __restrict__ k,
             const float* __restrict__ v,
             short* __restrict__ qb, short* __restrict__ kb,
             short* __restrict__ vt)
{
    __shared__ float tile[32][68];
    const int t  = threadIdx.x;
    const int bh = blockIdx.x;
    const int s0 = blockIdx.y * 32;
    const size_t base = ((size_t)bh * SEQ + s0) * DH;   // 32*64 f32 = 512 float4
    const size_t kbh  = (size_t)bh * SEQ * DH;

    #pragma unroll
    for (int i = 0; i < 2; ++i) {
        const int idx = i * 256 + t;
        float4 a = ((const float4*)(q + base))[idx];
        ((int2*)(qb + base))[idx] = make_int2(
            cvtpk(a.x * QSCALE, a.y * QSCALE),
            cvtpk(a.z * QSCALE, a.w * QSCALE));

        // K -> fragment-major
        float4 b = ((const float4*)(k + base))[idx];
        {
            const int sl   = idx >> 4;           // local row 0..31
            const int fgrp = idx & 15;           // float4-group = d0/4
            const int sblk = (s0 >> 4) + (sl >> 4);
            const int half = fgrp >> 3;
            const int quad = (fgrp >> 1) & 3;
            const int r04  = (fgrp & 1) * 4;
            short* p = kb + kbh + (size_t)sblk * 1024 + half * 512
                     + (quad * 16 + (sl & 15)) * 8 + r04;
            *(int2*)p = make_int2(cvtpk(b.x, b.y), cvtpk(b.z, b.w));
        }

        float4 c = ((const float4*)(v + base))[idx];
        const int sl = idx >> 4, cg = (idx & 15) * 4;
        *(float4*)(&tile[sl][cg]) = c;
    }
    __syncthreads();
    {
        const int dl = t >> 2;     // d index 0..63
        const int qq = t & 3;      // quarter within the 32-seq block
        float f[8];
        #pragma unroll
        for (int r = 0; r < 4; ++r) {
            f[r]     = tile[qq * 4 + r][dl];        // m=0 half
            f[4 + r] = tile[16 + qq * 4 + r][dl];   // m=1 half
        }
        short8 pc;
        ((int*)&pc)[0] = cvtpk(f[0], f[1]);
        ((int*)&pc)[1] = cvtpk(f[2], f[3]);
        ((int*)&pc)[2] = cvtpk(f[4], f[5]);
        ((int*)&pc)[3] = cvtpk(f[6], f[7]);
        // fragment-major: chunk (k32 = s0/32, dt = dl>>4), lane = qq*16+(dl&15)
        short* p = vt + kbh + (size_t)((s0 >> 5) * 4 + (dl >> 4)) * 512
                 + (qq * 16 + (dl & 15)) * 8;
        *(short8*)p = pc;
    }
}

// ---- main: 4-way split-K flash, 64 q-rows/wave (R10/R14 structure — FINAL).
// DO NOT REMOVE the s_setprio toggles: R12/R13 measured that deleting them
// (a semantically-neutral diff) produces deterministic NaN — they act as
// scheduling fences around the cvtpk inline-asm / MFMA / prefetch chain.
// DO NOT raise launch_bounds to (256,3): R15/R16 measured true register
// demand ~190 unified (bq32+o64+ka32+av32+pb/addr/temps); the 170-reg cap
// spills the accumulator (~600MB scratch traffic, attn 131us).
// History: fragment-major dense loads (R8, 2.3x), fixed-frame softmax (R6),
// shuffle-free PV via MFMA16 frag identity (R0-R2), V-hoist + K-prefetch-
// after-last-use (R5/R10), 64 q-rows/wave (R10).
// Nulls established: VALU diet, occupancy 8/12/24 w/CU, full-iter reg dbuf,
// LDS 2-phase staging (lost, 50.5us), L2-traffic /2 and /4, L1 sharing.
__global__ __launch_bounds__(256, 2)
void attn_fwd(const short* __restrict__ qb, const short* __restrict__ kb,
              const short* __restrict__ vt, float* __restrict__ og)
{
    __shared__ float lds_o[4][4][64][17];   // [wave][qs][lane][16] padded
    __shared__ float lds_l[4][4][16];

    const int lane = threadIdx.x & 63;
    const int wave = threadIdx.x >> 6;     // k-quarter 0..3
    const int quad = lane >> 4;
    const int l16  = lane & 15;
    const int lane8 = lane * 8;            // short offset of this lane's 16B

    // bijective XCD swizzle (768 = 8 XCD x 96): 3 bh per XCD -> K/V L2-resident
    const int swz = (blockIdx.x & 7) * 96 + (blockIdx.x >> 3);
    const int bh  = swz >> 5;              // 32 blocks per bh
    const int q0  = (swz & 31) * 64;       // 64 q-rows per block

    const short* kbase = kb + (size_t)bh * SEQ * DH;
    const short* vbase = vt + (size_t)bh * DH * SEQ;

    short8 bq[4][2];
    #pragma unroll
    for (int qs = 0; qs < 4; ++qs) {
        const short* qrow = qb + ((size_t)(bh * SEQ + q0 + qs * 16 + l16)) * DH + quad * 8;
        bq[qs][0] = *(const short8*)(qrow);
        bq[qs][1] = *(const short8*)(qrow + 32);
    }

    f32x4 o[4][4];
    float l_i[4];
    #pragma unroll
    for (int qs = 0; qs < 4; ++qs) {
        l_i[qs] = 0.f;
        #pragma unroll
        for (int dt = 0; dt < 4; ++dt) o[qs][dt] = (f32x4){0.f, 0.f, 0.f, 0.f};
    }

    int k0 = wave * (SEQ / 4);
    short8 ka[8];
    #pragma unroll
    for (int mt = 0; mt < 4; ++mt) {
        const short* kc = kbase + (size_t)((k0 >> 4) + mt) * 1024 + lane8;
        ka[2 * mt]     = *(const short8*)(kc);
        ka[2 * mt + 1] = *(const short8*)(kc + 512);
    }

    #pragma unroll 1
    for (int iter = 0; iter < 8; ++iter, k0 += 64) {
        // ---- V(i) loads first: dense 1KB segments
        short8 av[2][4];
        #pragma unroll
        for (int pair = 0; pair < 2; ++pair)
            #pragma unroll
            for (int dt = 0; dt < 4; ++dt)
                av[pair][dt] = *(const short8*)(vbase
                    + (size_t)((((k0 >> 5) + pair) * 4) + dt) * 512 + lane8);

        // ---- per q-subtile: QK^T -> fixed-frame exp2+pack -> PV (pb transient)
        #pragma unroll
        for (int qs = 0; qs < 4; ++qs) {
            f32x4 c[4];
            __builtin_amdgcn_s_setprio(1);
            #pragma unroll
            for (int mt = 0; mt < 4; ++mt) {
                f32x4 z = (f32x4){0.f, 0.f, 0.f, 0.f};
                z = MFMA32(ka[2 * mt],     bq[qs][0], z);
                z = MFMA32(ka[2 * mt + 1], bq[qs][1], z);
                c[mt] = z;
            }
            __builtin_amdgcn_s_setprio(0);

            // K(i+1) prefetch right after ka's last use (qs==3 QK^T)
            if (qs == 3 && iter < 7) {
                const int k0n = k0 + 64;
                #pragma unroll
                for (int mt = 0; mt < 4; ++mt) {
                    const short* kc = kbase + (size_t)((k0n >> 4) + mt) * 1024 + lane8;
                    ka[2 * mt]     = *(const short8*)(kc);
                    ka[2 * mt + 1] = *(const short8*)(kc + 512);
                }
            }

            // p = exp2(S) raw — fixed frame; cancels in (Sum p*v)/(Sum p).
            short4v pb[4];
            float rsm[4];
            #pragma unroll
            for (int mt = 0; mt < 4; ++mt) {
                float p[4];
                #pragma unroll
                for (int r = 0; r < 4; ++r)
                    p[r] = __builtin_amdgcn_exp2f(c[mt][r]);
                rsm[mt] = (p[0] + p[1]) + (p[2] + p[3]);
                int2 w = make_int2(cvtpk(p[0], p[1]), cvtpk(p[2], p[3]));
                pb[mt] = __builtin_bit_cast(short4v, w);
            }
            l_i[qs] += (rsm[0] + rsm[1]) + (rsm[2] + rsm[3]);

            // PV for this qs (av resident since iter top)
            __builtin_amdgcn_s_setprio(1);
            #pragma unroll
            for (int pair = 0; pair < 2; ++pair) {
                #pragma unroll
                for (int dt = 0; dt < 4; ++dt) {
                    const short4v alo = __builtin_shufflevector(av[pair][dt], av[pair][dt], 0, 1, 2, 3);
                    const short4v ahi = __builtin_shufflevector(av[pair][dt], av[pair][dt], 4, 5, 6, 7);
                    o[qs][dt] = MFMA16(alo, pb[2 * pair],     o[qs][dt]);
                    o[qs][dt] = MFMA16(ahi, pb[2 * pair + 1], o[qs][dt]);
                }
            }
            __builtin_amdgcn_s_setprio(0);
        }
    }

    // ---- finalize per-row l (cross-quad) once
    #pragma unroll
    for (int qs = 0; qs < 4; ++qs) {
        float l = l_i[qs];
        l += __shfl_xor(l, 16, 64);
        l += __shfl_xor(l, 32, 64);
        l_i[qs] = l;
    }

    // ---- 4-way cross-wave merge: all waves write partials; each wave
    // combines 4 of the 16 (qs,dt) slices.
    #pragma unroll
    for (int qs = 0; qs < 4; ++qs) {
        #pragma unroll
        for (int dt = 0; dt < 4; ++dt)
            #pragma unroll
            for (int r = 0; r < 4; ++r)
                lds_o[wave][qs][lane][dt * 4 + r] = o[qs][dt][r];
        if (quad == 0) lds_l[wave][qs][l16] = l_i[qs];
    }
    __syncthreads();
    #pragma unroll
    for (int j = 0; j < 4; ++j) {
        const int s  = wave * 4 + j;
        const int qs = s >> 2, dt = s & 3;
        const float L = (lds_l[0][qs][l16] + lds_l[1][qs][l16])
                      + (lds_l[2][qs][l16] + lds_l[3][qs][l16]);
        const float linv = 1.0f / L;
        f32x4 st;
        #pragma unroll
        for (int r = 0; r < 4; ++r)
            st[r] = ((lds_o[0][qs][lane][dt * 4 + r] + lds_o[1][qs][lane][dt * 4 + r])
                   + (lds_o[2][qs][lane][dt * 4 + r] + lds_o[3][qs][lane][dt * 4 + r]))
                  * linv;
        *(f32x4*)(og + ((size_t)(bh * SEQ + q0 + qs * 16 + l16)) * DH
                  + dt * 16 + quad * 4) = st;
    }
}

extern "C" void kernel_launch(void* const* d_in, const int* in_sizes, int n_in,
                              void* d_out, int out_size, void* d_ws, size_t ws_size,
                              hipStream_t stream)
{
    const float* q = (const float*)d_in[0];
    const float* k = (const float*)d_in[1];
    const float* v = (const float*)d_in[2];
    float* o = (float*)d_out;

    const size_t nelem = (size_t)NBH * SEQ * DH;
    short* qb  = (short*)d_ws;
    short* kbp = qb + nelem;
    short* vtp = kbp + nelem;   // 18.9 MB total

    cvt_all<<<dim3(NBH, SEQ / 32), 256, 0, stream>>>(q, k, v, qb, kbp, vtp);
    attn_fwd<<<dim3(NBH * (SEQ / 64)), 256, 0, stream>>>(qb, kbp, vtp, o);
    // grid = 24 bh x 32 q-tiles of 64 rows = 768 blocks
}